// Round 2
// baseline (745.892 us; speedup 1.0000x reference)
//
#include <hip/hip_runtime.h>
#include <math.h>

#define TT   34   // seq len
#define VV   14   // vocab
#define NROW 64   // rows per block (one per lane)
#define BLK  512  // 8 waves = 8 t-slots

// wsm layout (floats):
//  0..35  out_w (6x6)   36..41 ln2_g  42..47 ln2_b
// 48..65  ffn_w1        66..68 ffn_b1
// 69..86  ffn_w2        87..92 ffn_b2
// 93..98  lnf_g         99..104 lnf_b
// 105..188 M[v][d] = head_w.T @ tok_emb.T fused
// stab layout (floats):
//  0..41 tok_emb  42..143 pos_enc  144..149 ln1_g  150..155 ln1_b  156..173 q_w

__device__ __forceinline__ void epi_t(int t, int id, const float* a,
                                      const float* wsm, const float* stab,
                                      float* lg) {
    // softmax normalize
    const float i0 = 1.0f / a[0], i1 = 1.0f / a[1];
    const float o6[6] = { a[2]*i0, a[3]*i0, a[4]*i0, a[5]*i1, a[6]*i1, a[7]*i1 };
    // residual x (raw embed concat)
    float x[6];
    x[0] = stab[id*3+0]; x[1] = stab[id*3+1]; x[2] = stab[id*3+2];
    x[3] = stab[42+t*3+0]; x[4] = stab[42+t*3+1]; x[5] = stab[42+t*3+2];
    #pragma unroll
    for (int d = 0; d < 6; ++d) {
        float s = x[d];
        #pragma unroll
        for (int j = 0; j < 6; ++j) s += o6[j] * wsm[d*6+j];
        x[d] = s;
    }
    // LN2 + FFN (exact gelu) + residual
    {
        float mu = (x[0]+x[1]+x[2]+x[3]+x[4]+x[5]) * (1.0f/6.0f);
        float var = 0.f;
        #pragma unroll
        for (int d = 0; d < 6; ++d) { float dd = x[d]-mu; var += dd*dd; }
        const float rstd = rsqrtf(var*(1.0f/6.0f) + 1e-5f);
        float h2[6];
        #pragma unroll
        for (int d = 0; d < 6; ++d) h2[d] = (x[d]-mu)*rstd*wsm[36+d] + wsm[42+d];
        float g3[3];
        #pragma unroll
        for (int i = 0; i < 3; ++i) {
            float f = wsm[66+i];
            #pragma unroll
            for (int d = 0; d < 6; ++d) f += h2[d]*wsm[48+i*6+d];
            g3[i] = 0.5f * f * (1.0f + erff(f*0.70710678118654752f));
        }
        #pragma unroll
        for (int d = 0; d < 6; ++d) {
            float s = x[d] + wsm[87+d];
            #pragma unroll
            for (int i = 0; i < 3; ++i) s += g3[i]*wsm[69+d*3+i];
            x[d] = s;
        }
    }
    // LNF + fused head
    {
        float mu = (x[0]+x[1]+x[2]+x[3]+x[4]+x[5]) * (1.0f/6.0f);
        float var = 0.f;
        #pragma unroll
        for (int d = 0; d < 6; ++d) { float dd = x[d]-mu; var += dd*dd; }
        const float rstd = rsqrtf(var*(1.0f/6.0f) + 1e-5f);
        float xf[6];
        #pragma unroll
        for (int d = 0; d < 6; ++d) xf[d] = (x[d]-mu)*rstd*wsm[93+d] + wsm[99+d];
        #pragma unroll
        for (int v = 0; v < VV; ++v) {
            float s = 0.f;
            #pragma unroll
            for (int d = 0; d < 6; ++d) s += xf[d]*wsm[105+v*6+d];
            lg[v] = s;
        }
    }
}

#define ATT_BODY(J) do { \
    float sc0 = q[J][0]*ka.x + q[J][1]*ka.y + q[J][2]*ka.z; \
    float sc1 = q[J][3]*ka.w + q[J][4]*kb.x + q[J][5]*kb.y; \
    float p0 = exp2f(sc0); \
    float p1 = exp2f(sc1); \
    acc[J][0] += p0;       acc[J][1] += p1; \
    acc[J][2] += p0*kb.z;  acc[J][3] += p0*kb.w;  acc[J][4] += p0*vb.x; \
    acc[J][5] += p1*vb.y;  acc[J][6] += p1*vb.z;  acc[J][7] += p1*vb.w; \
} while (0)

template<int G>
__device__ __forceinline__ void slot_run(int t0, const int* __restrict__ lrow,
                                         const float4* __restrict__ kvt,
                                         const float* __restrict__ wsm,
                                         const float* __restrict__ stab,
                                         float* __restrict__ outp) {
    const float qs = 1.4426950408889634f;  // log2(e); k already carries 1/sqrt(3)
    float q[G][6];
    float acc[G][8];
    #pragma unroll
    for (int j = 0; j < G; ++j) {
        const int t = t0 + j;
        const int id = lrow[t];
        const float x0 = stab[id*3+0], x1 = stab[id*3+1], x2 = stab[id*3+2];
        const float x3 = stab[42+t*3+0], x4 = stab[42+t*3+1], x5 = stab[42+t*3+2];
        const float mu = (x0+x1+x2+x3+x4+x5) * (1.0f/6.0f);
        const float d0=x0-mu,d1=x1-mu,d2=x2-mu,d3=x3-mu,d4=x4-mu,d5=x5-mu;
        const float var = d0*d0+d1*d1+d2*d2+d3*d3+d4*d4+d5*d5;
        const float rstd = rsqrtf(var*(1.0f/6.0f) + 1e-5f);
        const float h3 = d3*rstd*stab[147] + stab[153];
        const float h4 = d4*rstd*stab[148] + stab[154];
        const float h5 = d5*rstd*stab[149] + stab[155];
        #pragma unroll
        for (int r = 0; r < 6; ++r)
            q[j][r] = (h3*stab[156+r*3] + h4*stab[156+r*3+1] + h5*stab[156+r*3+2]) * qs;
        #pragma unroll
        for (int k = 0; k < 8; ++k) acc[j][k] = 0.f;
    }
    // main phase: all G t's active for s <= t0
    for (int s = 0; s <= t0; ++s) {
        const int ids = lrow[s];
        const float4* e4 = &kvt[(s*VV + ids)*3];
        const float4 ka = e4[0], kb = e4[1], vb = e4[2];
        #pragma unroll
        for (int j = 0; j < G; ++j) ATT_BODY(j);
    }
    // ragged tail: s = t0+u, only t >= s active
    #pragma unroll
    for (int u = 1; u < G; ++u) {
        const int s = t0 + u;
        const int ids = lrow[s];
        const float4* e4 = &kvt[(s*VV + ids)*3];
        const float4 ka = e4[0], kb = e4[1], vb = e4[2];
        #pragma unroll
        for (int j = u; j < G; ++j) ATT_BODY(j);
    }
    // epilogue per t-pair -> 28 floats -> 7 aligned float4 stores
    #pragma unroll
    for (int p = 0; p < G/2; ++p) {
        alignas(16) float lg[28];
        #pragma unroll
        for (int h = 0; h < 2; ++h) {
            const int j = 2*p + h, t = t0 + j;
            epi_t(t, lrow[t], acc[j], wsm, stab, &lg[14*h]);
        }
        float4* d4 = (float4*)(outp + (t0 + 2*p)*VV);
        const float4* s4 = (const float4*)lg;
        #pragma unroll
        for (int w = 0; w < 7; ++w) d4[w] = s4[w];
    }
}

__global__ __launch_bounds__(BLK, 4) void addtx_fwd(
    const int*   __restrict__ idx,
    const float* __restrict__ tok_emb, const float* __restrict__ pos_enc,
    const float* __restrict__ q_w, const float* __restrict__ k_w,
    const float* __restrict__ v_w, const float* __restrict__ out_w,
    const float* __restrict__ ln1_g, const float* __restrict__ ln1_b,
    const float* __restrict__ ln2_g, const float* __restrict__ ln2_b,
    const float* __restrict__ lnf_g, const float* __restrict__ lnf_b,
    const float* __restrict__ ffn_w1, const float* __restrict__ ffn_b1,
    const float* __restrict__ ffn_w2, const float* __restrict__ ffn_b2,
    const float* __restrict__ head_w,
    float* __restrict__ out)
{
    __shared__ float4 kvtab[TT*VV*3];   // 22848 B ; k pre-scaled 1/sqrt(3)
    __shared__ float  wsm[192];         // 768 B
    __shared__ float  stab[176];        // 704 B
    __shared__ int    lidx[NROW*35];    // 8960 B (stride 35 kills 4-way conflicts)

    const int tid = threadIdx.x;
    const int blk = blockIdx.x;

    // ---- stage epilogue weights ----
    if (tid < 189) {
        const int i = tid;
        float w;
        if (i < 36)       w = out_w[i];
        else if (i < 42)  w = ln2_g[i-36];
        else if (i < 48)  w = ln2_b[i-42];
        else if (i < 66)  w = ffn_w1[i-48];
        else if (i < 69)  w = ffn_b1[i-66];
        else if (i < 87)  w = ffn_w2[i-69];
        else if (i < 93)  w = ffn_b2[i-87];
        else if (i < 99)  w = lnf_g[i-93];
        else if (i < 105) w = lnf_b[i-99];
        else {
            const int j = i-105, v = j/6, d = j-v*6;
            w = head_w[0*6+d]*tok_emb[v*3+0] + head_w[1*6+d]*tok_emb[v*3+1]
              + head_w[2*6+d]*tok_emb[v*3+2];
        }
        wsm[i] = w;
    } else if (tid < 192 + 174 && tid >= 192) {
        const int i = tid - 192;
        float w;
        if (i < 42)        w = tok_emb[i];
        else if (i < 144)  w = pos_enc[i-42];
        else if (i < 150)  w = ln1_g[i-144];
        else if (i < 156)  w = ln1_b[i-150];
        else               w = q_w[i-156];
        stab[i] = w;
    }

    // ---- build (pos,tok) -> k,v table (one entry per thread) ----
    if (tid < TT*VV) {
        const int e = tid;
        const int pos = e / VV, id = e - pos*VV;
        const float rs3 = 0.57735026918962576f;
        float x[6];
        x[0]=tok_emb[id*3+0]; x[1]=tok_emb[id*3+1]; x[2]=tok_emb[id*3+2];
        x[3]=pos_enc[pos*3+0]; x[4]=pos_enc[pos*3+1]; x[5]=pos_enc[pos*3+2];
        float mu = (x[0]+x[1]+x[2]+x[3]+x[4]+x[5]) * (1.0f/6.0f);
        float var = 0.f;
        #pragma unroll
        for (int d = 0; d < 6; ++d) { float dd = x[d]-mu; var += dd*dd; }
        const float rstd = rsqrtf(var*(1.0f/6.0f) + 1e-5f);
        float h[6];
        #pragma unroll
        for (int d = 0; d < 6; ++d) h[d] = (x[d]-mu)*rstd*ln1_g[d] + ln1_b[d];
        float kk[6], vv[6];
        #pragma unroll
        for (int r = 0; r < 6; ++r) {
            kk[r] = (h[3]*k_w[r*3+0] + h[4]*k_w[r*3+1] + h[5]*k_w[r*3+2]) * rs3;
            vv[r] =  h[0]*v_w[r*3+0] + h[1]*v_w[r*3+1] + h[2]*v_w[r*3+2];
        }
        kvtab[e*3+0] = make_float4(kk[0],kk[1],kk[2],kk[3]);
        kvtab[e*3+1] = make_float4(kk[4],kk[5],vv[0],vv[1]);
        kvtab[e*3+2] = make_float4(vv[2],vv[3],vv[4],vv[5]);
    }

    // ---- stage this block's idx rows (coalesced) ----
    for (int j = tid; j < NROW*TT; j += BLK) {
        const int r = j / TT, c = j - r*TT;
        lidx[r*35 + c] = idx[(size_t)blk * (NROW*TT) + j];
    }
    __syncthreads();

    // ---- slot per wave, row per lane ----
    const int wv = tid >> 6, lane = tid & 63;
    const int t0 = wv * 4;                          // slot 7: t0=28, G=6
    const int b  = blk * NROW + lane;
    const int* lrow = &lidx[lane*35];
    float* outp = out + (size_t)b * (TT*VV);

    if (wv < 7) slot_run<4>(t0, lrow, kvtab, wsm, stab, outp);
    else        slot_run<6>(t0, lrow, kvtab, wsm, stab, outp);
}

extern "C" void kernel_launch(void* const* d_in, const int* in_sizes, int n_in,
                              void* d_out, int out_size, void* d_ws, size_t ws_size,
                              hipStream_t stream) {
    const int*   idx     = (const int*)  d_in[0];
    const float* tok_emb = (const float*)d_in[1];
    const float* pos_enc = (const float*)d_in[2];
    const float* q_w     = (const float*)d_in[3];
    const float* k_w     = (const float*)d_in[4];
    const float* v_w     = (const float*)d_in[5];
    const float* out_w   = (const float*)d_in[6];
    const float* ln1_g   = (const float*)d_in[7];
    const float* ln1_b   = (const float*)d_in[8];
    const float* ln2_g   = (const float*)d_in[9];
    const float* ln2_b   = (const float*)d_in[10];
    const float* lnf_g   = (const float*)d_in[11];
    const float* lnf_b   = (const float*)d_in[12];
    const float* ffn_w1  = (const float*)d_in[13];
    const float* ffn_b1  = (const float*)d_in[14];
    const float* ffn_w2  = (const float*)d_in[15];
    const float* ffn_b2  = (const float*)d_in[16];
    const float* head_w  = (const float*)d_in[17];
    float* out = (float*)d_out;

    const int rows   = in_sizes[0] / TT;   // 65536
    const int blocks = rows / NROW;        // 1024
    addtx_fwd<<<blocks, BLK, 0, stream>>>(idx, tok_emb, pos_enc, q_w, k_w, v_w, out_w,
                                          ln1_g, ln1_b, ln2_g, ln2_b, lnf_g, lnf_b,
                                          ffn_w1, ffn_b1, ffn_w2, ffn_b2, head_w, out);
}

// Round 3
// 288.447 us; speedup vs baseline: 2.5859x; 2.5859x over previous
//
#include <hip/hip_runtime.h>
#include <math.h>

#define TT   34
#define VV   14
#define NROW 64
#define BLK  512
#define NE   (TT*VV)   // 476
#define SSTR 114       // stage row stride in floats (even; 57 mod 16 = 9 coprime 16)

#if __has_builtin(__builtin_amdgcn_exp2f)
#define EXP2(x) __builtin_amdgcn_exp2f(x)
#else
#define EXP2(x) exp2f(x)
#endif

// wsm: 0..35 out_w | 36..41 ln2_g | 42..47 ln2_b | 48..65 ffn_w1 | 66..68 ffn_b1
//      69..86 ffn_w2 | 87..92 ffn_b2 | 93..98 lnf_g | 99..104 lnf_b | 105..188 M[v][d]
// stab: 0..41 tok_emb | 42..143 pos_enc | 144..149 ln1_g | 150..155 ln1_b | 156..173 q_w

__device__ __forceinline__ void epi(int t, int id, const float* a,
                                    const float* wsm, const float* stab,
                                    float* lg) {
    const float i0 = 1.0f / a[0], i1 = 1.0f / a[1];
    const float o6[6] = { a[2]*i0, a[3]*i0, a[4]*i0, a[5]*i1, a[6]*i1, a[7]*i1 };
    float x[6];
    x[0] = stab[id*3+0]; x[1] = stab[id*3+1]; x[2] = stab[id*3+2];
    x[3] = stab[42+t*3+0]; x[4] = stab[42+t*3+1]; x[5] = stab[42+t*3+2];
    #pragma unroll
    for (int d = 0; d < 6; ++d) {
        float s = x[d];
        #pragma unroll
        for (int j = 0; j < 6; ++j) s += o6[j] * wsm[d*6+j];
        x[d] = s;
    }
    {   // LN2 + FFN (exact gelu) + residual
        float mu = (x[0]+x[1]+x[2]+x[3]+x[4]+x[5]) * (1.0f/6.0f);
        float var = 0.f;
        #pragma unroll
        for (int d = 0; d < 6; ++d) { float dd = x[d]-mu; var += dd*dd; }
        const float rstd = rsqrtf(var*(1.0f/6.0f) + 1e-5f);
        float h2[6];
        #pragma unroll
        for (int d = 0; d < 6; ++d) h2[d] = (x[d]-mu)*rstd*wsm[36+d] + wsm[42+d];
        float g3[3];
        #pragma unroll
        for (int i = 0; i < 3; ++i) {
            float f = wsm[66+i];
            #pragma unroll
            for (int d = 0; d < 6; ++d) f += h2[d]*wsm[48+i*6+d];
            g3[i] = 0.5f * f * (1.0f + erff(f*0.70710678118654752f));
        }
        #pragma unroll
        for (int d = 0; d < 6; ++d) {
            float s = x[d] + wsm[87+d];
            #pragma unroll
            for (int i = 0; i < 3; ++i) s += g3[i]*wsm[69+d*3+i];
            x[d] = s;
        }
    }
    {   // LNF + fused head
        float mu = (x[0]+x[1]+x[2]+x[3]+x[4]+x[5]) * (1.0f/6.0f);
        float var = 0.f;
        #pragma unroll
        for (int d = 0; d < 6; ++d) { float dd = x[d]-mu; var += dd*dd; }
        const float rstd = rsqrtf(var*(1.0f/6.0f) + 1e-5f);
        float xf[6];
        #pragma unroll
        for (int d = 0; d < 6; ++d) xf[d] = (x[d]-mu)*rstd*wsm[93+d] + wsm[99+d];
        #pragma unroll
        for (int v = 0; v < VV; ++v) {
            float s = 0.f;
            #pragma unroll
            for (int d = 0; d < 6; ++d) s += xf[d]*wsm[105+v*6+d];
            lg[v] = s;
        }
    }
}

// Main attention loop: wave w owns t_j = w+8j (j<4), plus t_4 = 32+w when J==5.
// Segments lo=0..J-1: s in (ts[lo-1], ts[lo]] runs bodies j>=lo — wave-uniform bounds.
template<int J>
__device__ __forceinline__ void mainloop(const int w, const int* __restrict__ lrow,
    const float4* __restrict__ ka_t, const float4* __restrict__ kb_t,
    const float4* __restrict__ vb_t, const float* __restrict__ stab,
    float acc[5][8])
{
    int ts[J];
    #pragma unroll
    for (int j = 0; j < J; ++j) ts[j] = (j < 4) ? (w + 8*j) : (32 + w);

    const float qs = 1.4426950408889634f;   // log2(e); k carries 1/sqrt(3)
    float q[J][6];
    #pragma unroll
    for (int j = 0; j < J; ++j) {
        const int t = ts[j];
        const int id = lrow[t];
        const float x0 = stab[id*3+0], x1 = stab[id*3+1], x2 = stab[id*3+2];
        const float x3 = stab[42+t*3+0], x4 = stab[42+t*3+1], x5 = stab[42+t*3+2];
        const float mu = (x0+x1+x2+x3+x4+x5) * (1.0f/6.0f);
        const float d0=x0-mu,d1=x1-mu,d2=x2-mu,d3=x3-mu,d4=x4-mu,d5=x5-mu;
        const float var = d0*d0+d1*d1+d2*d2+d3*d3+d4*d4+d5*d5;
        const float rstd = rsqrtf(var*(1.0f/6.0f) + 1e-5f);
        const float h3 = d3*rstd*stab[147] + stab[153];
        const float h4 = d4*rstd*stab[148] + stab[154];
        const float h5 = d5*rstd*stab[149] + stab[155];
        #pragma unroll
        for (int r = 0; r < 6; ++r)
            q[j][r] = (h3*stab[156+r*3] + h4*stab[156+r*3+1] + h5*stab[156+r*3+2]) * qs;
        #pragma unroll
        for (int k = 0; k < 8; ++k) acc[j][k] = 0.f;
    }

    int sb = 0;
    #pragma unroll
    for (int lo = 0; lo < J; ++lo) {
        for (int s = sb; s <= ts[lo]; ++s) {
            const int ids = lrow[s];
            const int e = s*VV + ids;
            const float4 ka = ka_t[e];
            const float4 kb = kb_t[e];
            const float4 vb = vb_t[e];
            #pragma unroll
            for (int j = lo; j < J; ++j) {
                const float sc0 = q[j][0]*ka.x + q[j][1]*ka.y + q[j][2]*ka.z;
                const float sc1 = q[j][3]*ka.w + q[j][4]*kb.x + q[j][5]*kb.y;
                const float p0 = EXP2(sc0);
                const float p1 = EXP2(sc1);
                acc[j][0] += p0;       acc[j][1] += p1;
                acc[j][2] += p0*kb.z;  acc[j][3] += p0*kb.w;  acc[j][4] += p0*vb.x;
                acc[j][5] += p1*vb.y;  acc[j][6] += p1*vb.z;  acc[j][7] += p1*vb.w;
            }
        }
        sb = ts[lo] + 1;
    }
}

__global__ __launch_bounds__(BLK, 4) void addtx_fwd(
    const int*   __restrict__ idx,
    const float* __restrict__ tok_emb, const float* __restrict__ pos_enc,
    const float* __restrict__ q_w, const float* __restrict__ k_w,
    const float* __restrict__ v_w, const float* __restrict__ out_w,
    const float* __restrict__ ln1_g, const float* __restrict__ ln1_b,
    const float* __restrict__ ln2_g, const float* __restrict__ ln2_b,
    const float* __restrict__ lnf_g, const float* __restrict__ lnf_b,
    const float* __restrict__ ffn_w1, const float* __restrict__ ffn_b1,
    const float* __restrict__ ffn_w2, const float* __restrict__ ffn_b2,
    const float* __restrict__ head_w,
    float* __restrict__ out)
{
    __shared__ float4 ka_t[NE];          // k0..k3              7616 B
    __shared__ float4 kb_t[NE];          // k4,k5,v0,v1         7616 B
    __shared__ float4 vb_t[NE];          // v2..v5              7616 B
    __shared__ float  stg[NROW*SSTR];    // logits staging     29184 B
    __shared__ float  wsm[192];
    __shared__ float  stab[176];
    __shared__ int    lidx[NROW*35];     // idx rows, stride 35  8960 B

    const int tid = threadIdx.x;
    const int blk = blockIdx.x;

    // ---- stage epilogue weights / small tables ----
    if (tid < 189) {
        const int i = tid;
        float w;
        if (i < 36)       w = out_w[i];
        else if (i < 42)  w = ln2_g[i-36];
        else if (i < 48)  w = ln2_b[i-42];
        else if (i < 66)  w = ffn_w1[i-48];
        else if (i < 69)  w = ffn_b1[i-66];
        else if (i < 87)  w = ffn_w2[i-69];
        else if (i < 93)  w = ffn_b2[i-87];
        else if (i < 99)  w = lnf_g[i-93];
        else if (i < 105) w = lnf_b[i-99];
        else {
            const int j = i-105, v = j/6, d = j-v*6;
            w = head_w[0*6+d]*tok_emb[v*3+0] + head_w[1*6+d]*tok_emb[v*3+1]
              + head_w[2*6+d]*tok_emb[v*3+2];
        }
        wsm[i] = w;
    } else if (tid >= 256 && tid < 256 + 174) {
        const int i = tid - 256;
        float w;
        if (i < 42)        w = tok_emb[i];
        else if (i < 144)  w = pos_enc[i-42];
        else if (i < 150)  w = ln1_g[i-144];
        else if (i < 156)  w = ln1_b[i-150];
        else               w = q_w[i-156];
        stab[i] = w;
    }

    // ---- build (pos,tok) -> k,v SoA tables ----
    if (tid < NE) {
        const int e = tid;
        const int pos = e / VV, id = e - pos*VV;
        const float rs3 = 0.57735026918962576f;
        float x[6];
        x[0]=tok_emb[id*3+0]; x[1]=tok_emb[id*3+1]; x[2]=tok_emb[id*3+2];
        x[3]=pos_enc[pos*3+0]; x[4]=pos_enc[pos*3+1]; x[5]=pos_enc[pos*3+2];
        float mu = (x[0]+x[1]+x[2]+x[3]+x[4]+x[5]) * (1.0f/6.0f);
        float var = 0.f;
        #pragma unroll
        for (int d = 0; d < 6; ++d) { float dd = x[d]-mu; var += dd*dd; }
        const float rstd = rsqrtf(var*(1.0f/6.0f) + 1e-5f);
        float h[6];
        #pragma unroll
        for (int d = 0; d < 6; ++d) h[d] = (x[d]-mu)*rstd*ln1_g[d] + ln1_b[d];
        float kk[6], vv[6];
        #pragma unroll
        for (int r = 0; r < 6; ++r) {
            kk[r] = (h[3]*k_w[r*3+0] + h[4]*k_w[r*3+1] + h[5]*k_w[r*3+2]) * rs3;
            vv[r] =  h[0]*v_w[r*3+0] + h[1]*v_w[r*3+1] + h[2]*v_w[r*3+2];
        }
        ka_t[e] = make_float4(kk[0],kk[1],kk[2],kk[3]);
        kb_t[e] = make_float4(kk[4],kk[5],vv[0],vv[1]);
        vb_t[e] = make_float4(vv[2],vv[3],vv[4],vv[5]);
    }

    // ---- stage idx rows (coalesced, stride-35 in LDS) ----
    for (int j = tid; j < NROW*TT; j += BLK) {
        const int r = j / TT, c = j - r*TT;
        lidx[r*35 + c] = idx[(size_t)blk * (NROW*TT) + j];
    }
    __syncthreads();

    const int wv = tid >> 6, lane = tid & 63;
    const int* lrow = &lidx[lane*35];

    float acc[5][8];
    if (wv < 2) mainloop<5>(wv, lrow, ka_t, kb_t, vb_t, stab, acc);
    else        mainloop<4>(wv, lrow, ka_t, kb_t, vb_t, stab, acc);

    // ---- 5 staged, coalesced output phases ----
    float* __restrict__ outB = out + (size_t)blk * (NROW*TT*VV);
    #pragma unroll 1
    for (int P = 0; P < 5; ++P) {
        const bool writer = (P < 4) || (wv < 2);
        if (writer) {
            const int j = (P < 4) ? P : 4;
            const int t = (P < 4) ? (wv + 8*P) : (32 + wv);
            const int id = lrow[t];
            float lg[14];
            epi(t, id, acc[j], wsm, stab, lg);
            // c = (t - 8P)*14 + v = wv*14 + v in both cases
            float* sp = &stg[lane*SSTR + wv*14];
            #pragma unroll
            for (int i = 0; i < 7; ++i)
                *(float2*)(sp + 2*i) = make_float2(lg[2*i], lg[2*i+1]);
        }
        __syncthreads();
        if (P < 4) {
            // copy 64 rows x 112 floats (t = 8P..8P+7) -> 1792 float4s
            #pragma unroll
            for (int k = 0; k < 4; ++k) {
                const int f = tid + k*BLK;
                if (f < 1792) {
                    const int row = f / 28, c4 = f - row*28;
                    const float* rp = &stg[row*SSTR + c4*4];
                    const float2 v0 = *(const float2*)rp;
                    const float2 v1 = *(const float2*)(rp+2);
                    *(float4*)(outB + row*(TT*VV) + P*112 + c4*4) =
                        make_float4(v0.x, v0.y, v1.x, v1.y);
                }
            }
        } else {
            // tail: t = 32,33 -> 64 rows x 28 floats = 448 float4s
            if (tid < 448) {
                const int row = tid / 7, c4 = tid - row*7;
                const float* rp = &stg[row*SSTR + c4*4];
                const float2 v0 = *(const float2*)rp;
                const float2 v1 = *(const float2*)(rp+2);
                *(float4*)(outB + row*(TT*VV) + 448 + c4*4) =
                    make_float4(v0.x, v0.y, v1.x, v1.y);
            }
        }
        __syncthreads();
    }
}

extern "C" void kernel_launch(void* const* d_in, const int* in_sizes, int n_in,
                              void* d_out, int out_size, void* d_ws, size_t ws_size,
                              hipStream_t stream) {
    const int*   idx     = (const int*)  d_in[0];
    const float* tok_emb = (const float*)d_in[1];
    const float* pos_enc = (const float*)d_in[2];
    const float* q_w     = (const float*)d_in[3];
    const float* k_w     = (const float*)d_in[4];
    const float* v_w     = (const float*)d_in[5];
    const float* out_w   = (const float*)d_in[6];
    const float* ln1_g   = (const float*)d_in[7];
    const float* ln1_b   = (const float*)d_in[8];
    const float* ln2_g   = (const float*)d_in[9];
    const float* ln2_b   = (const float*)d_in[10];
    const float* lnf_g   = (const float*)d_in[11];
    const float* lnf_b   = (const float*)d_in[12];
    const float* ffn_w1  = (const float*)d_in[13];
    const float* ffn_b1  = (const float*)d_in[14];
    const float* ffn_w2  = (const float*)d_in[15];
    const float* ffn_b2  = (const float*)d_in[16];
    const float* head_w  = (const float*)d_in[17];
    float* out = (float*)d_out;

    const int rows   = in_sizes[0] / TT;   // 65536
    const int blocks = rows / NROW;        // 1024
    addtx_fwd<<<blocks, BLK, 0, stream>>>(idx, tok_emb, pos_enc, q_w, k_w, v_w, out_w,
                                          ln1_g, ln1_b, ln2_g, ln2_b, lnf_g, lnf_b,
                                          ffn_w1, ffn_b1, ffn_w2, ffn_b2, head_w, out);
}